// Round 3
// baseline (5656.761 us; speedup 1.0000x reference)
//
#include <hip/hip_runtime.h>

#define Dd 256
#define Nn 128
#define Hh 32
#define HSk 20
#define Tt 256
#define NWG 128
#define NT 256
#define ETAf 1e-3f

// ------------- coherent (L1/L2-bypassing) access helpers -------------
__device__ __forceinline__ unsigned ld_ag(const unsigned* p) {
  return __hip_atomic_load(p, __ATOMIC_RELAXED, __HIP_MEMORY_SCOPE_AGENT);
}
__device__ __forceinline__ void st_ag(unsigned* p, unsigned v) {
  __hip_atomic_store(p, v, __ATOMIC_RELAXED, __HIP_MEMORY_SCOPE_AGENT);
}
__device__ __forceinline__ float ldg_c(const float* p) {
  return __hip_atomic_load(p, __ATOMIC_RELAXED, __HIP_MEMORY_SCOPE_AGENT);
}
__device__ __forceinline__ void stg_c(float* p, float v) {
  __hip_atomic_store(p, v, __ATOMIC_RELAXED, __HIP_MEMORY_SCOPE_AGENT);
}
__device__ __forceinline__ void atadd_c(float* p, float v) {
  __hip_atomic_fetch_add(p, v, __ATOMIC_RELAXED, __HIP_MEMORY_SCOPE_AGENT);
}

// ---------------- flat all-to-all barrier: 1 store + 1 poll round trip ----
__device__ __forceinline__ void grid_sync(unsigned* flags, unsigned b) {
  asm volatile("s_waitcnt vmcnt(0)" ::: "memory");  // data stores committed to L3
  __syncthreads();
  if (threadIdx.x == 0) st_ag(&flags[blockIdx.x], b);
  if (threadIdx.x < NWG) {
    while (ld_ag(&flags[threadIdx.x]) < b) {}
  }
  asm volatile("" ::: "memory");
  __syncthreads();
}

__global__ void init_ws_kernel(unsigned* bar, float* uacc) {
  for (int i = threadIdx.x; i < NWG; i += 256) bar[i] = 0u;
  for (int i = threadIdx.x; i < 2 * Nn; i += 256) uacc[i] = 0.f;
}

// ---------------- main persistent kernel ----------------
__global__ __launch_bounds__(NT, 1)
void osf_main(const float* __restrict__ Am, const float* __restrict__ Bm,
              const float* __restrict__ Qmat, const float* __restrict__ Rm,
              const float* __restrict__ Km, const float* __restrict__ phi,
              const float* __restrict__ sigma, const float* __restrict__ phis,
              const float* __restrict__ M0, const float* __restrict__ Ms,
              const float* __restrict__ x0, const float* __restrict__ W0,
              float* __restrict__ out, unsigned* __restrict__ bar,
              float* __restrict__ fws) {
  const int g = blockIdx.x;
  const int tid = threadIdx.x;
  unsigned* flags = bar;

  float* uacc = fws;                   // [2][128]  u accumulator (atomicAdd target)
  float* vbuf = uacc + 2 * Nn;         // [32][256] v_t stored [h][d]
  float* phT  = vbuf + Hh * Dd;        // [20][128] P_hist transposed [k][n]
  float* xs   = phT + HSk * Nn;        // [256][256] x_t history (row t valid t>=1)
  float* u2   = xs + (size_t)Tt * Dd;  // [256][128] u_t history (same-WG use only)

  __shared__ float s_u[Nn], s_urow[Tt], s_w[2][Tt];
  __shared__ float s_x[Dd], s_S[2][Nn], s_A[2][Dd], s_B[2][Nn], s_K[Dd];
  __shared__ float s_g[32], s_xh[2], s_red[16], s_pre5[NT], s_pre4[NT], s_w0[2];

  const int h = g >> 2;          // owned filter index (M slice)
  const int n0 = (g & 3) * 32;   // owned n-range base (M slice)
  const int jj = tid >> 3;       // 0..31: n within slice
  const int dsub = tid & 7;      // 0..7: 32-wide d chunk
  const float sig4h = sqrtf(sqrtf(sigma[h]));

  // ---- init: per-WG constant rows into LDS (ordinary cached loads) ----
  for (int i = tid; i < Dd; i += NT) {
    s_A[0][i] = Am[(2 * g) * Dd + i];
    s_A[1][i] = Am[(2 * g + 1) * Dd + i];
    s_K[i] = Km[g * Dd + i];
  }
  for (int i = tid; i < Nn; i += NT) {
    float a0 = 0.f, a1 = 0.f;
    for (int k = 0; k < HSk; ++k) {             // S[d,:] = sum_k phis[0,k]*M_stu[k,d,:]
      a0 += phis[k] * Ms[(k * Dd + 2 * g) * Nn + i];
      a1 += phis[k] * Ms[(k * Dd + 2 * g + 1) * Nn + i];
    }
    s_S[0][i] = a0;
    s_S[1][i] = a1;
    s_B[0][i] = Bm[(2 * g) * Nn + i];
    s_B[1][i] = Bm[(2 * g + 1) * Nn + i];
  }
  if (tid < 2) s_w0[tid] = W0[(2 * g + tid) * 512];   // W0[:,0] only nonzero col
  s_pre5[tid] = 0.f;
  s_pre4[tid] = 0.f;

  // M slice resident in registers: M[h][n0+jj][dsub*32 .. +32]
  float Mreg[32], vp[32];
  {
    const float* mp = M0 + ((size_t)(h * Nn + n0 + jj) * Dd + dsub * 32);
#pragma unroll
    for (int e = 0; e < 32; ++e) {
      Mreg[e] = mp[e];
      vp[e] = 0.f;
    }
  }
  __syncthreads();

  unsigned b = 0;
  for (int t = 0;; ++t) {
    // =================== P phase ===================
    if (t > 0) {
      if (tid < Nn) {  // u_{t-1}: one load; zero the parity buffer for reuse at t+2
        const float uv = ldg_c(&uacc[(t & 1) * Nn + tid]);
        stg_c(&uacc[(t & 1) * Nn + tid], 0.f);
        s_u[tid] = uv;
      }
      __syncthreads();
      if (tid < Nn && ((t - 1) & 127) == g) u2[(size_t)(t - 1) * Nn + tid] = s_u[tid];
      if (tid == 0) s_urow[t - 1] = s_u[g];
      {  // g_{t-1} = 2 R u for owned n-slice
        float p = 0.f;
        const float* rr = Rm + (n0 + jj) * Nn + dsub * 16;
#pragma unroll
        for (int q = 0; q < 16; ++q) p += rr[q] * s_u[dsub * 16 + q];
        p += __shfl_xor(p, 1);
        p += __shfl_xor(p, 2);
        p += __shfl_xor(p, 4);
        if (dsub == 0) s_g[jj] = 2.f * p;
      }
      if (t < Tt && tid < 128) {  // x_t, new_w_{t-1} for owned d-pair (waves 0,1)
        const int dd = tid >> 6, l = tid & 63;
        float pS = s_S[dd][l] * s_u[l] + s_S[dd][l + 64] * s_u[l + 64];
        float pB = s_B[dd][l] * s_u[l] + s_B[dd][l + 64] * s_u[l + 64];
        float pA = 0.f;
#pragma unroll
        for (int q = 0; q < 4; ++q) pA += s_A[dd][l + 64 * q] * s_x[l + 64 * q];
#pragma unroll
        for (int off = 1; off < 64; off <<= 1) {
          pS += __shfl_xor(pS, off);
          pB += __shfl_xor(pB, off);
          pA += __shfl_xor(pA, off);
        }
        if (l == 0) {
          const float xt = s_xh[dd] + pS;          // x_t = x_hist_{t-1} + S u_{t-1}
          s_w[dd][t - 1] = xt - pA - pB;           // new_w_{t-1} = x_t - A x_{t-1} - B u_{t-1}
          stg_c(&xs[(size_t)t * Dd + 2 * g + dd], xt);
        }
      }
      __syncthreads();
    }
    if (t == Tt) break;

    if (tid < 64) {  // v_t combine: precomputed old-history + newest w term + W0 term
      const int dd = tid >> 5, h5 = tid & 31;
      float v = s_w0[dd] * phi[t * Hh + h5];
      if (t > 0) v += s_w[dd][t - 1] * phi[h5];
#pragma unroll
      for (int q = 0; q < 4; ++q) v += s_pre5[dd * 128 + q * 32 + h5];
      stg_c(&vbuf[h5 * Dd + 2 * g + dd], v);
    }
    if (t > 0 && tid < HSk) {  // phT combine: precomputed + newest u term
      float p = s_u[g] * phis[HSk + tid];
#pragma unroll
      for (int q = 0; q < 8; ++q) p += s_pre4[q * 32 + tid];
      stg_c(&phT[tid * Nn + g], p);
    }

    grid_sync(flags, ++b);

    // =================== Q phase ===================
    const float xreg = (t == 0) ? x0[tid] : ldg_c(&xs[(size_t)t * Dd + tid]);

    float vc[32];  // issue all v loads first: latency hides under conv precompute
    {
      const float* vrow = vbuf + h * Dd + dsub * 32;
#pragma unroll
      for (int e = 0; e < 32; ++e) vc[e] = ldg_c(vrow + e);
    }

    float accx = 0.f;
    if (t > 0) {  // x_hist partial: Ms row dot phT (bypassed loads, issued early)
      const int dd = tid >> 7, n = tid & 127;
      const int d = 2 * g + dd;
#pragma unroll
      for (int k = 0; k < HSk; ++k)
        accx += Ms[((size_t)k * Dd + d) * Nn + n] * ldg_c(&phT[k * Nn + n]);
    }

    {  // conv precompute for NEXT step's P (runs under the load latency above)
      const int dd = tid >> 7, r = tid & 127;
      const int s5 = r >> 5, h5 = r & 31;
      float a5 = 0.f;
      for (int s = s5; s < t; s += 4) a5 += s_w[dd][s] * phi[(t - s) * Hh + h5];
      s_pre5[tid] = a5;
      const int ssub = tid >> 5, lane = tid & 31;
      float a4 = 0.f;
      if (lane < HSk) {
        for (int s = ssub; s < t; s += 8) a4 += s_urow[s] * phis[(t + 1 - s) * HSk + lane];
      }
      s_pre4[tid] = a4;
    }

    {  // fused M SGD update (with v_{t-1}) + dot with v_t -> atomicAdd into u_{t}
      float coef = (t > 0) ? (ETAf * sig4h * s_g[jj]) : 0.f;
      float acc = 0.f;
#pragma unroll
      for (int e = 0; e < 32; ++e) {
        Mreg[e] -= coef * vp[e];
        acc += Mreg[e] * vc[e];
        vp[e] = vc[e];
      }
      acc += __shfl_xor(acc, 1);
      acc += __shfl_xor(acc, 2);
      acc += __shfl_xor(acc, 4);
      if (dsub == 0) atadd_c(&uacc[((t + 1) & 1) * Nn + n0 + jj], sig4h * acc);
    }

    {  // reductions: x_hist halves -> s_xh; kx -> atomicAdd -K contribution
      float acck = s_K[tid] * xreg;
#pragma unroll
      for (int off = 1; off < 64; off <<= 1) {
        accx += __shfl_xor(accx, off);
        acck += __shfl_xor(acck, off);
      }
      if ((tid & 63) == 0) {
        s_red[tid >> 6] = accx;
        s_red[8 + (tid >> 6)] = acck;
      }
      s_x[tid] = xreg;  // x_t for next P's A-dot
      __syncthreads();
      if (tid < 2) s_xh[tid] = s_red[2 * tid] + s_red[2 * tid + 1];
      if (tid == 0)
        atadd_c(&uacc[((t + 1) & 1) * Nn + g],
                -(s_red[8] + s_red[9] + s_red[10] + s_red[11]));
    }

    grid_sync(flags, ++b);
  }

  // =================== deferred losses pass ===================
  for (int tt = g; tt < Tt; tt += NWG) {
    __syncthreads();
    s_x[tid] = (tt == 0) ? x0[tid] : ldg_c(&xs[(size_t)tt * Dd + tid]);
    __syncthreads();
    float qp = 0.f;
    for (int d2 = 0; d2 < Dd; ++d2) qp += Qmat[d2 * Dd + tid] * s_x[d2];
    float tot = qp * s_x[tid];                       // (x^T Q)[tid] * x[tid]
    if (tid < Nn) {
      const float un = u2[(size_t)tt * Nn + tid];
      float rp = 0.f;
      for (int n2 = 0; n2 < Nn; ++n2) rp += Rm[n2 * Nn + tid] * u2[(size_t)tt * Nn + n2];
      tot += un * rp;                                // u^T R u contribution
    }
#pragma unroll
    for (int off = 1; off < 64; off <<= 1) tot += __shfl_xor(tot, off);
    __syncthreads();
    if ((tid & 63) == 0) s_red[tid >> 6] = tot;
    __syncthreads();
    if (tid == 0) out[tt] = s_red[0] + s_red[1] + s_red[2] + s_red[3];
  }
}

extern "C" void kernel_launch(void* const* d_in, const int* in_sizes, int n_in,
                              void* d_out, int out_size, void* d_ws, size_t ws_size,
                              hipStream_t stream) {
  (void)in_sizes; (void)n_in; (void)out_size; (void)ws_size;
  const float* A   = (const float*)d_in[0];
  const float* B   = (const float*)d_in[1];
  const float* Qm  = (const float*)d_in[2];
  const float* R   = (const float*)d_in[3];
  const float* K   = (const float*)d_in[4];
  const float* phi = (const float*)d_in[5];
  const float* sig = (const float*)d_in[6];
  const float* phs = (const float*)d_in[7];
  const float* M0  = (const float*)d_in[8];
  const float* Ms  = (const float*)d_in[9];
  const float* x0  = (const float*)d_in[10];
  const float* W0  = (const float*)d_in[11];
  // d_in[12] = U0 (all zeros, unused)

  unsigned* bar = (unsigned*)d_ws;
  float* fws = (float*)((char*)d_ws + 12288);

  // flags + u-accumulators must be re-zeroed every call (ws poisoned once only)
  init_ws_kernel<<<1, 256, 0, stream>>>(bar, fws);
  osf_main<<<NWG, NT, 0, stream>>>(A, B, Qm, R, K, phi, sig, phs, M0, Ms, x0, W0,
                                   (float*)d_out, bar, fws);
}

// Round 4
// 5500.632 us; speedup vs baseline: 1.0284x; 1.0284x over previous
//
#include <hip/hip_runtime.h>

#define Dd 256
#define Nn 128
#define Hh 32
#define HSk 20
#define Tt 256
#define NWG 32
#define NT 1024
#define ETAf 1e-3f

// ------------- coherent (L1/L2-bypassing) access helpers -------------
__device__ __forceinline__ unsigned ld_ag(const unsigned* p) {
  return __hip_atomic_load(p, __ATOMIC_RELAXED, __HIP_MEMORY_SCOPE_AGENT);
}
__device__ __forceinline__ void st_ag(unsigned* p, unsigned v) {
  __hip_atomic_store(p, v, __ATOMIC_RELAXED, __HIP_MEMORY_SCOPE_AGENT);
}
__device__ __forceinline__ float ldg_c(const float* p) {
  return __hip_atomic_load(p, __ATOMIC_RELAXED, __HIP_MEMORY_SCOPE_AGENT);
}
__device__ __forceinline__ void stg_c(float* p, float v) {
  __hip_atomic_store(p, v, __ATOMIC_RELAXED, __HIP_MEMORY_SCOPE_AGENT);
}

// full-wave (64 lane) sum; result valid in lane 0 of each wave
__device__ __forceinline__ float wred64(float p) {
  p += __shfl_xor(p, 1);  p += __shfl_xor(p, 2);  p += __shfl_xor(p, 4);
  p += __shfl_xor(p, 8);  p += __shfl_xor(p, 16); p += __shfl_xor(p, 32);
  return p;
}

__global__ void init_ws_kernel(unsigned* bar) {
  for (int i = threadIdx.x; i < 2 * NWG * 16; i += 256) bar[i] = 0u;
}

// ---------------- main persistent kernel ----------------
__global__ __launch_bounds__(NT, 4)
void osf_main(const float* __restrict__ Am, const float* __restrict__ Bm,
              const float* __restrict__ Qmat, const float* __restrict__ Rm,
              const float* __restrict__ Km, const float* __restrict__ phi,
              const float* __restrict__ sigma, const float* __restrict__ phis,
              const float* __restrict__ M0, const float* __restrict__ Ms,
              const float* __restrict__ x0, const float* __restrict__ W0,
              float* __restrict__ out, unsigned* __restrict__ bar,
              float* __restrict__ fws) {
  const int g = blockIdx.x;
  const int tid = threadIdx.x;

  unsigned* hflag = bar;              // [32*16] mid-step handoff flags
  unsigned* bflag = bar + NWG * 16;   // [32*16] end-step barrier flags

  float* vpub  = fws;                 // [32 h][256 d]  v_t
  float* phpub = vpub + Hh * Dd;      // [20 k][128 n]  phT-pre for x_{t+1}
  float* us    = phpub + HSk * Nn;    // [256 t][128 n] u history
  float* xs    = us + Tt * Nn;        // [256 t][256 d] x history (t>=1)

  const int d0 = 8 * g;   // owned d rows
  const int n0 = 4 * g;   // owned n cols

  const int h  = tid >> 5;        // 0..31 filter
  const int nn = (tid >> 3) & 3;  // 0..3 n within slice
  const int q  = tid & 7;         // 0..7 d-chunk (32 each)

  __shared__ float s_v[Hh * 264];     // v_t staged, skewed [h][q*33+e]
  __shared__ float s_php[HSk * Nn];   // phT-pre staged
  __shared__ float whist[8][Tt];      // own-d w history
  __shared__ float uh[4][Tt];         // own-n u history
  __shared__ float s_S0[8][Nn];       // S0 = sum_k phis[0,k] Ms[k,d_own,:]
  __shared__ float s_u[Nn], s_x[Dd];
  __shared__ float s_prev[8][Hh];     // pre_v for current step's v
  __shared__ float s_g[4], s_cn[Hh * 4], s_kx[4], s_xc8[8], s_Bu8[8], s_w8[8],
      s_Axp[8], s_prex[8], s_red[16], s_w0v[8];

  const float sig4h = sqrtf(sqrtf(sigma[h]));

  // ---------------- init ----------------
  {
    const int dp = tid >> 7, j = tid & 127;   // 1024 = 8*128
    float a = 0.f;
    for (int k = 0; k < HSk; ++k)
      a += phis[k] * Ms[((size_t)k * Dd + d0 + dp) * Nn + j];
    s_S0[dp][j] = a;
    if (tid < 256) {
      const int dp2 = tid >> 5, hh = tid & 31;
      s_prev[dp2][hh] = W0[(d0 + dp2) * 512] * phi[hh];  // v_0 = w0 * phi[0,h]
    }
    if (tid < 8) {
      s_w0v[tid] = W0[(d0 + tid) * 512];
      s_w8[tid] = 0.f; s_prex[tid] = 0.f; s_Axp[tid] = 0.f;
    }
  }

  // M slice in registers: M[h][n0+nn][q*32 .. +32]
  float Mreg[32], vp[32];
  {
    const float* mp = M0 + ((size_t)(h * Nn + n0 + nn) * Dd + q * 32);
#pragma unroll
    for (int e = 0; e < 32; ++e) { Mreg[e] = mp[e]; vp[e] = 0.f; }
  }
  __syncthreads();

  for (int t = 0; t < Tt; ++t) {
    // ============ P: advance state with u_{t-1} ============
    if (t > 0) {
      if (tid < Nn) s_u[tid] = ldg_c(&us[(t - 1) * Nn + tid]);
      __syncthreads();
      if (tid < 4) uh[tid][t - 1] = s_u[n0 + tid];
      if (tid < 256) {            // g[n'] = 2 (R u)[n0+n']
        const int np = tid >> 6, c = tid & 63;
        float p = Rm[(n0 + np) * Nn + c] * s_u[c] +
                  Rm[(n0 + np) * Nn + c + 64] * s_u[c + 64];
        p = wred64(p);
        if ((tid & 63) == 0) s_g[np] = 2.f * p;
      } else if (tid < 512) {     // x_t[d'] = pre_x + S0 u
        const int r = tid - 256, dp = r >> 5, l = r & 31;
        float p = 0.f;
        for (int j2 = 0; j2 < 4; ++j2) p += s_S0[dp][l + 32 * j2] * s_u[l + 32 * j2];
        p += __shfl_xor(p, 1); p += __shfl_xor(p, 2); p += __shfl_xor(p, 4);
        p += __shfl_xor(p, 8); p += __shfl_xor(p, 16);
        if (l == 0) s_xc8[dp] = s_prex[dp] + p;
      } else if (tid < 768) {     // (B u)[d']
        const int r = tid - 512, dp = r >> 5, l = r & 31;
        float p = 0.f;
        for (int j2 = 0; j2 < 4; ++j2)
          p += Bm[(d0 + dp) * Nn + l + 32 * j2] * s_u[l + 32 * j2];
        p += __shfl_xor(p, 1); p += __shfl_xor(p, 2); p += __shfl_xor(p, 4);
        p += __shfl_xor(p, 8); p += __shfl_xor(p, 16);
        if (l == 0) s_Bu8[dp] = p;
      }
      __syncthreads();
      if (tid < 8) {              // w_{t-1}[d'] = x_t - A x_{t-1} - B u_{t-1}
        const float wv = s_xc8[tid] - s_Axp[tid] - s_Bu8[tid];
        whist[tid][t - 1] = wv;
        s_w8[tid] = wv;
      }
      __syncthreads();
    }

    // publish v_t, x_t, phT-pre_{t+1}
    if (tid < 256) {
      const int dp = tid >> 5, hh = tid & 31;
      stg_c(&vpub[hh * Dd + d0 + dp], s_prev[dp][hh] + s_w8[dp] * phi[hh]);
    } else if (tid < 264) {
      if (t > 0) stg_c(&xs[(size_t)t * Dd + d0 + (tid - 256)], s_xc8[tid - 256]);
    } else if (tid >= 320 && tid < 960) {
      const int r = tid - 320;                  // 640 = 4n * 20k * 8sub
      const int np = r / 160, rem = r - np * 160, k = rem >> 3, sub = rem & 7;
      float p = 0.f;
      for (int s = sub; s < t; s += 8) p += uh[np][s] * phis[(t - s) * HSk + k];
      p += __shfl_xor(p, 1); p += __shfl_xor(p, 2); p += __shfl_xor(p, 4);
      if (sub == 0) stg_c(&phpub[k * Nn + n0 + np], p);
    }
    asm volatile("s_waitcnt vmcnt(0)" ::: "memory");
    __syncthreads();
    if (tid == 0) st_ag(&hflag[g * 16], (unsigned)(t + 1));

    // ============ handoff wait + stage ============
    if (tid < NWG) {
      while (ld_ag(&hflag[tid * 16]) < (unsigned)(t + 1)) __builtin_amdgcn_s_sleep(1);
    }
    asm volatile("" ::: "memory");
    __syncthreads();
#pragma unroll
    for (int i = 0; i < 8; ++i) {
      const int idx = tid * 8 + i;              // linear [h][d]
      const int hh = idx >> 8, dl = idx & 255;
      s_v[hh * 264 + dl + (dl >> 5)] = ldg_c(&vpub[idx]);
    }
    if (tid < 256) s_x[tid] = (t == 0) ? x0[tid] : ldg_c(&xs[(size_t)t * Dd + tid]);
    if (tid < 640) {
#pragma unroll
      for (int i = 0; i < 4; ++i) {
        const int idx = tid * 4 + i;
        s_php[idx] = ldg_c(&phpub[idx]);
      }
    }
    __syncthreads();

    // ============ Q: M update + cn + u assembly ============
    {
      const float coef = (t > 0) ? (ETAf * sig4h * s_g[nn]) : 0.f;
      float acc = 0.f;
      const float* vrow = &s_v[h * 264 + q * 33];
#pragma unroll
      for (int e = 0; e < 32; ++e) {
        const float vce = vrow[e];
        Mreg[e] -= coef * vp[e];
        acc += Mreg[e] * vce;
        vp[e] = vce;
      }
      acc += __shfl_xor(acc, 1); acc += __shfl_xor(acc, 2); acc += __shfl_xor(acc, 4);
      if (q == 0) s_cn[h * 4 + nn] = sig4h * acc;
    }
    if (tid < 256) {              // kx[n'] = K[n0+n',:] . x_t
      const int np = tid >> 6, c = tid & 63;
      float p = 0.f;
      for (int j2 = 0; j2 < 4; ++j2)
        p += Km[(n0 + np) * Dd + c + 64 * j2] * s_x[c + 64 * j2];
      p = wred64(p);
      if ((tid & 63) == 0) s_kx[np] = p;
    }
    __syncthreads();
    if (tid < 4) {
      float uu = -s_kx[tid];
      for (int hh = 0; hh < Hh; ++hh) uu += s_cn[hh * 4 + tid];
      stg_c(&us[(size_t)t * Nn + n0 + tid], uu);
    }
    asm volatile("s_waitcnt vmcnt(0)" ::: "memory");
    __syncthreads();
    if (tid == 0) st_ag(&bflag[g * 16], (unsigned)(t + 1));

    // ============ slack: precompute for step t+1 (flags already set) ========
    {
      const int dp = tid >> 7;
      const int r = tid & 127, hh = r >> 2, sub = r & 3;
      float p = 0.f;                       // pre_v_{t+1}[d', h]
      for (int s = sub; s < t; s += 4)
        p += whist[dp][s] * phi[(t - s) * Hh + hh];
      p += __shfl_xor(p, 1); p += __shfl_xor(p, 2);

      const int j = tid & 127;             // fold pre_x_{t+1}[d'] partials
      float fx = 0.f;
      for (int k = 0; k < HSk; ++k)
        fx += Ms[((size_t)k * Dd + d0 + dp) * Nn + j] * s_php[k * Nn + j];
      fx = wred64(fx);

      float ax = 0.f;                      // (A x_t)[d'] partials
      if (tid < 512) {
        const int dp2 = tid >> 6, c = tid & 63;
        for (int j2 = 0; j2 < 4; ++j2)
          ax += Am[(d0 + dp2) * Dd + c + 64 * j2] * s_x[c + 64 * j2];
        ax = wred64(ax);
      }
      if (sub == 0) s_prev[dp][hh] = p + s_w0v[dp] * phi[(t + 1) * Hh + hh];
      if ((tid & 63) == 0) s_red[tid >> 6] = fx;
      if (tid < 512 && (tid & 63) == 0) s_Axp[tid >> 6] = ax;
      __syncthreads();
      if (tid < 8) s_prex[tid] = s_red[2 * tid] + s_red[2 * tid + 1];
    }

    // ============ end-of-step barrier ============
    if (tid < NWG) {
      while (ld_ag(&bflag[tid * 16]) < (unsigned)(t + 1)) __builtin_amdgcn_s_sleep(1);
    }
    asm volatile("" ::: "memory");
    __syncthreads();
  }

  // =================== deferred losses pass ===================
  for (int tt = g; tt < Tt; tt += NWG) {
    __syncthreads();
    if (tid < 256) s_x[tid] = (tt == 0) ? x0[tid] : ldg_c(&xs[(size_t)tt * Dd + tid]);
    if (tid < 128) s_u[tid] = ldg_c(&us[(size_t)tt * Nn + tid]);
    __syncthreads();
    float tot = 0.f;
    if (tid < 256) {
      float qp = 0.f;
      for (int d2 = 0; d2 < Dd; ++d2) qp += Qmat[d2 * Dd + tid] * s_x[d2];
      tot = qp * s_x[tid];
    }
    if (tid < 128) {
      float rp = 0.f;
      for (int n2 = 0; n2 < Nn; ++n2) rp += Rm[n2 * Nn + tid] * s_u[n2];
      tot += s_u[tid] * rp;
    }
    tot = wred64(tot);
    if ((tid & 63) == 0) s_red[tid >> 6] = tot;
    __syncthreads();
    if (tid == 0) {
      float ss = 0.f;
      for (int i2 = 0; i2 < 16; ++i2) ss += s_red[i2];
      out[tt] = ss;
    }
  }
}

extern "C" void kernel_launch(void* const* d_in, const int* in_sizes, int n_in,
                              void* d_out, int out_size, void* d_ws, size_t ws_size,
                              hipStream_t stream) {
  (void)in_sizes; (void)n_in; (void)out_size; (void)ws_size;
  const float* A   = (const float*)d_in[0];
  const float* B   = (const float*)d_in[1];
  const float* Qm  = (const float*)d_in[2];
  const float* R   = (const float*)d_in[3];
  const float* K   = (const float*)d_in[4];
  const float* phi = (const float*)d_in[5];
  const float* sig = (const float*)d_in[6];
  const float* phs = (const float*)d_in[7];
  const float* M0  = (const float*)d_in[8];
  const float* Ms  = (const float*)d_in[9];
  const float* x0  = (const float*)d_in[10];
  const float* W0  = (const float*)d_in[11];
  // d_in[12] = U0 (all zeros, unused)

  unsigned* bar = (unsigned*)d_ws;
  float* fws = (float*)((char*)d_ws + 4096);

  // flags must be re-zeroed every call (ws poisoned once, never restored)
  init_ws_kernel<<<1, 256, 0, stream>>>(bar);
  osf_main<<<NWG, NT, 0, stream>>>(A, B, Qm, R, K, phi, sig, phs, M0, Ms, x0, W0,
                                   (float*)d_out, bar, fws);
}

// Round 5
// 4530.948 us; speedup vs baseline: 1.2485x; 1.2140x over previous
//
#include <hip/hip_runtime.h>

#define Dd 256
#define Nn 128
#define Hh 32
#define HSk 20
#define Tt 256
#define NWG 128
#define NT 256
#define ETAf 1e-3f

typedef unsigned long long u64;

// ------------- coherent (L1/L2-bypassing) access helpers -------------
__device__ __forceinline__ u64 ld64(const u64* p) {
  return __hip_atomic_load(p, __ATOMIC_RELAXED, __HIP_MEMORY_SCOPE_AGENT);
}
__device__ __forceinline__ void st64(u64* p, u64 v) {
  __hip_atomic_store(p, v, __ATOMIC_RELAXED, __HIP_MEMORY_SCOPE_AGENT);
}
__device__ __forceinline__ float ldg_c(const float* p) {
  return __hip_atomic_load(p, __ATOMIC_RELAXED, __HIP_MEMORY_SCOPE_AGENT);
}
__device__ __forceinline__ void stg_c(float* p, float v) {
  __hip_atomic_store(p, v, __ATOMIC_RELAXED, __HIP_MEMORY_SCOPE_AGENT);
}
__device__ __forceinline__ u64 pack(float v, unsigned tag) {
  return ((u64)tag << 32) | (u64)__float_as_uint(v);
}
__device__ __forceinline__ float val_of(u64 r) {
  return __uint_as_float((unsigned)r);
}
__device__ __forceinline__ unsigned tag_of(u64 r) { return (unsigned)(r >> 32); }

__device__ __forceinline__ float wred64(float p) {
  p += __shfl_xor(p, 1);  p += __shfl_xor(p, 2);  p += __shfl_xor(p, 4);
  p += __shfl_xor(p, 8);  p += __shfl_xor(p, 16); p += __shfl_xor(p, 32);
  return p;
}

#define N_TAGGED (128 + Hh * Dd + Dd + Hh * Nn + 2 * HSk * Nn)

__global__ void init_ws_kernel(u64* w) {
  const int i = blockIdx.x * 256 + threadIdx.x;
  if (i < N_TAGGED) w[i] = 0ull;
}

// ---------------- main persistent kernel: tagged dataflow, no barriers ----
__global__ __launch_bounds__(NT, 1)
void osf_main(const float* __restrict__ Am, const float* __restrict__ Bm,
              const float* __restrict__ Qmat, const float* __restrict__ Rm,
              const float* __restrict__ Km, const float* __restrict__ phi,
              const float* __restrict__ sigma, const float* __restrict__ phis,
              const float* __restrict__ M0, const float* __restrict__ Ms,
              const float* __restrict__ x0, const float* __restrict__ W0,
              float* __restrict__ out, u64* __restrict__ wsb) {
  const int g = blockIdx.x;
  const int tid = threadIdx.x;

  u64* TD = wsb;                 // [128]      done flags
  u64* TV = TD + 128;            // [32h][256d] v_t tagged
  u64* TX = TV + Hh * Dd;        // [256d]      x_t tagged
  u64* TC = TX + Dd;             // [32h][128n] cn partial tagged
  u64* TP = TC + Hh * Nn;        // [2][20k][128n] phT tagged (parity dbuf)
  float* us = (float*)(TP + 2 * HSk * Nn);  // [256t][128n]
  float* xs = us + Tt * Nn;                 // [256t][256d]

  __shared__ float s_u[Nn], s_uL[Nn], s_x[Dd], s_w[2][Tt], s_urow[Tt];
  __shared__ float s_S[2][Nn], s_A[2][Dd], s_B[2][Nn];
  __shared__ float s_g[32], s_xh[2], s_red[16], s_pre5[NT], s_pre4[NT];
  __shared__ float s_w0[2], s_wc[2], s_xc[2];

  const int h = g >> 2;          // owned filter (M slice)
  const int n0 = (g & 3) * 32;   // owned n base (M slice)
  const int jj = tid >> 3;       // n within slice
  const int dsub = tid & 7;      // 32-wide d chunk
  const int d0 = 2 * g;          // owned d pair
  const float sig4h = sqrtf(sqrtf(sigma[h]));

  // ---- init LDS constants ----
  for (int i = tid; i < Dd; i += NT) {
    s_A[0][i] = Am[d0 * Dd + i];
    s_A[1][i] = Am[(d0 + 1) * Dd + i];
  }
  for (int i = tid; i < Nn; i += NT) {
    float a0 = 0.f, a1 = 0.f;
    for (int k = 0; k < HSk; ++k) {
      a0 += phis[k] * Ms[((size_t)k * Dd + d0) * Nn + i];
      a1 += phis[k] * Ms[((size_t)k * Dd + d0 + 1) * Nn + i];
    }
    s_S[0][i] = a0; s_S[1][i] = a1;
    s_B[0][i] = Bm[d0 * Nn + i];
    s_B[1][i] = Bm[(d0 + 1) * Nn + i];
  }
  if (tid < 2) { s_w0[tid] = W0[(d0 + tid) * 512]; s_xh[tid] = 0.f; }
  s_pre5[tid] = 0.f;
  s_pre4[tid] = 0.f;

  float Mreg[32], vp[32];
  {
    const float* mp = M0 + ((size_t)(h * Nn + n0 + jj) * Dd + dsub * 32);
#pragma unroll
    for (int e = 0; e < 32; ++e) { Mreg[e] = mp[e]; vp[e] = 0.f; }
  }
  __syncthreads();

  for (int t = 0; t < Tt; ++t) {
    const unsigned want = (unsigned)(t + 1);

    // ================= P: advance state with u_{t-1} (local) =================
    if (t > 0) {
      {  // g[jj] = 2 (R u)[n0+jj]
        float p = 0.f;
        const float* rr = Rm + (n0 + jj) * Nn + dsub * 16;
#pragma unroll
        for (int q = 0; q < 16; ++q) p += rr[q] * s_u[dsub * 16 + q];
        p += __shfl_xor(p, 1); p += __shfl_xor(p, 2); p += __shfl_xor(p, 4);
        if (dsub == 0) s_g[jj] = 2.f * p;
      }
      if (tid < 128) {  // x_t, w_{t-1} for owned d-pair
        const int dd = tid >> 6, l = tid & 63;
        float pS = s_S[dd][l] * s_u[l] + s_S[dd][l + 64] * s_u[l + 64];
        float pB = s_B[dd][l] * s_u[l] + s_B[dd][l + 64] * s_u[l + 64];
        float pA = 0.f;
#pragma unroll
        for (int q = 0; q < 4; ++q) pA += s_A[dd][l + 64 * q] * s_x[l + 64 * q];
#pragma unroll
        for (int off = 1; off < 64; off <<= 1) {
          pS += __shfl_xor(pS, off);
          pB += __shfl_xor(pB, off);
          pA += __shfl_xor(pA, off);
        }
        if (l == 0) {
          const float xt = s_xh[dd] + pS;
          const float wv = xt - pA - pB;
          s_w[dd][t - 1] = wv;
          s_wc[dd] = wv;
          s_xc[dd] = xt;
        }
      }
      __syncthreads();
    }

    // ================= publish v_t, x_t, phT (tagged, fire-and-forget) ======
    if (tid < 64) {
      const int dd = tid >> 5, h5 = tid & 31;
      float v = s_w0[dd] * phi[t * Hh + h5];
      if (t > 0) v += s_wc[dd] * phi[h5];
#pragma unroll
      for (int q = 0; q < 4; ++q) v += s_pre5[dd * 128 + q * 32 + h5];
      st64(&TV[h5 * Dd + d0 + dd], pack(v, want));
    } else if (tid < 66) {
      if (t > 0) {
        st64(&TX[d0 + tid - 64], pack(s_xc[tid - 64], want));
        stg_c(&xs[(size_t)t * Dd + d0 + tid - 64], s_xc[tid - 64]);
      }
    } else if (tid >= 96 && tid < 96 + HSk) {
      if (t > 0) {
        const int k = tid - 96;
        float p = s_u[g] * phis[HSk + k];
#pragma unroll
        for (int q = 0; q < 8; ++q) p += s_pre4[q * 32 + k];
        st64(&TP[(t & 1) * HSk * Nn + k * Nn + g], pack(p, want));
      }
    }
    __syncthreads();

    // ================= Q =================
    // x_t (1 slot per thread)
    if (t > 0) {
      u64 rx;
      for (;;) {
        rx = ld64(&TX[tid]);
        if (tag_of(rx) >= want) break;
        __builtin_amdgcn_s_sleep(1);
      }
      s_x[tid] = val_of(rx);
    } else {
      s_x[tid] = x0[tid];
    }
    // distributed v poll: each thread guards 4 of the WG's 256 v slots
    {
      const int e0 = (jj & 7) * 4;
      bool ok;
      do {
        u64 r4[4];
        ok = true;
#pragma unroll
        for (int i = 0; i < 4; ++i) r4[i] = ld64(&TV[h * Dd + dsub * 32 + e0 + i]);
#pragma unroll
        for (int i = 0; i < 4; ++i) ok &= (tag_of(r4[i]) >= want);
        if (!ok) __builtin_amdgcn_s_sleep(1);
      } while (!ok);
    }
    __syncthreads();  // all 256 v slots of row h verified tagged; s_x ready

    float vc[32];
    {
      u64 raw[32];
#pragma unroll
      for (int e = 0; e < 32; ++e) raw[e] = ld64(&TV[h * Dd + dsub * 32 + e]);
#pragma unroll
      for (int e = 0; e < 32; ++e) vc[e] = val_of(raw[e]);
    }

    {  // fused M SGD update + dot -> publish cn partial
      const float coef = (t > 0) ? (ETAf * sig4h * s_g[jj]) : 0.f;
      float acc = 0.f;
#pragma unroll
      for (int e = 0; e < 32; ++e) {
        Mreg[e] -= coef * vp[e];
        acc += Mreg[e] * vc[e];
        vp[e] = vc[e];
      }
      acc += __shfl_xor(acc, 1); acc += __shfl_xor(acc, 2); acc += __shfl_xor(acc, 4);
      if (dsub == 0) st64(&TC[h * Nn + n0 + jj], pack(sig4h * acc, want));
    }

    // kx[n] replicated locally (hides under cn round trip)
    float kxv;
    {
      const int n = tid >> 1, half = tid & 1;
      float p = 0.f;
      const float* kr = Km + (size_t)n * Dd + half * 128;
#pragma unroll 16
      for (int q = 0; q < 128; ++q) p += kr[q] * s_x[half * 128 + q];
      p += __shfl_xor(p, 1);
      kxv = p;
    }

    // accx: fold Ms . phT (tagged poll, slack) -> s_red
    if (t > 0) {
      const int dd = tid >> 7, n = tid & 127;
      const u64* tp = &TP[(t & 1) * HSk * Nn + n];
      u64 rp[HSk];
      bool ok;
      do {
        ok = true;
#pragma unroll
        for (int k = 0; k < HSk; ++k) rp[k] = ld64(&tp[k * Nn]);
#pragma unroll
        for (int k = 0; k < HSk; ++k) ok &= (tag_of(rp[k]) >= want);
        if (!ok) __builtin_amdgcn_s_sleep(1);
      } while (!ok);
      float fx = 0.f;
#pragma unroll
      for (int k = 0; k < HSk; ++k)
        fx += Ms[((size_t)k * Dd + d0 + dd) * Nn + n] * val_of(rp[k]);
      fx = wred64(fx);
      if ((tid & 63) == 0) s_red[tid >> 6] = fx;
    }

    {  // pre5: v-conv partials for step t+1
      const int dd = tid >> 7, r = tid & 127, s5 = r >> 5, h5 = r & 31;
      float a5 = 0.f;
      for (int s = s5; s < t; s += 4) a5 += s_w[dd][s] * phi[(t - s) * Hh + h5];
      s_pre5[tid] = a5;
    }
    {  // pre4: phT-conv partials for step t+1
      const int ssub = tid >> 5, lane = tid & 31;
      float a4 = 0.f;
      if (lane < HSk) {
        for (int s = ssub; s < t; s += 8)
          a4 += s_urow[s] * phis[(t + 1 - s) * HSk + lane];
      }
      s_pre4[tid] = a4;
    }

    {  // u_t assembly: poll cn column, subtract kx (every WG gets full u)
      const int n = tid >> 1, half = tid & 1;
      u64 rc[16];
      bool ok;
      do {
        ok = true;
#pragma unroll
        for (int i = 0; i < 16; ++i) rc[i] = ld64(&TC[(half * 16 + i) * Nn + n]);
#pragma unroll
        for (int i = 0; i < 16; ++i) ok &= (tag_of(rc[i]) >= want);
        if (!ok) __builtin_amdgcn_s_sleep(1);
      } while (!ok);
      float up = 0.f;
#pragma unroll
      for (int i = 0; i < 16; ++i) up += val_of(rc[i]);
      up += __shfl_xor(up, 1);
      if (half == 0) s_u[n] = up - kxv;
    }
    __syncthreads();
    if (t > 0 && tid < 2) s_xh[tid] = s_red[2 * tid] + s_red[2 * tid + 1];
    if (tid == 0) {
      s_urow[t] = s_u[g];
      stg_c(&us[(size_t)t * Nn + g], s_u[g]);
    }
    __syncthreads();
  }

  // ---------------- final done-barrier (guarantees us/xs visible) ----------
  asm volatile("s_waitcnt vmcnt(0)" ::: "memory");
  __syncthreads();
  if (tid == 0) st64(&TD[g], pack(0.f, Tt));
  {
    u64 r;
    for (;;) {
      r = ld64(&TD[tid & 127]);
      if (tag_of(r) >= (unsigned)Tt) break;
      __builtin_amdgcn_s_sleep(1);
    }
  }
  __syncthreads();

  // ---------------- deferred losses ----------------
  for (int tt = g; tt < Tt; tt += NWG) {
    __syncthreads();
    s_x[tid] = (tt == 0) ? x0[tid] : ldg_c(&xs[(size_t)tt * Dd + tid]);
    if (tid < Nn)
      s_uL[tid] = (tt == Tt - 1) ? s_u[tid] : ldg_c(&us[(size_t)tt * Nn + tid]);
    __syncthreads();
    float tot = 0.f;
    {
      float qp = 0.f;
      for (int d2 = 0; d2 < Dd; ++d2) qp += Qmat[d2 * Dd + tid] * s_x[d2];
      tot = qp * s_x[tid];
    }
    if (tid < Nn) {
      float rp = 0.f;
      for (int n2 = 0; n2 < Nn; ++n2) rp += Rm[n2 * Nn + tid] * s_uL[n2];
      tot += s_uL[tid] * rp;
    }
    tot = wred64(tot);
    if ((tid & 63) == 0) s_red[tid >> 6] = tot;
    __syncthreads();
    if (tid == 0) out[tt] = s_red[0] + s_red[1] + s_red[2] + s_red[3];
  }
}

extern "C" void kernel_launch(void* const* d_in, const int* in_sizes, int n_in,
                              void* d_out, int out_size, void* d_ws, size_t ws_size,
                              hipStream_t stream) {
  (void)in_sizes; (void)n_in; (void)out_size; (void)ws_size;
  const float* A   = (const float*)d_in[0];
  const float* B   = (const float*)d_in[1];
  const float* Qm  = (const float*)d_in[2];
  const float* R   = (const float*)d_in[3];
  const float* K   = (const float*)d_in[4];
  const float* phi = (const float*)d_in[5];
  const float* sig = (const float*)d_in[6];
  const float* phs = (const float*)d_in[7];
  const float* M0  = (const float*)d_in[8];
  const float* Ms  = (const float*)d_in[9];
  const float* x0  = (const float*)d_in[10];
  const float* W0  = (const float*)d_in[11];
  // d_in[12] = U0 (zeros, unused)

  u64* wsb = (u64*)d_ws;
  // all tagged slots must be re-zeroed every call (ws poisoned once only)
  init_ws_kernel<<<(N_TAGGED + 255) / 256, 256, 0, stream>>>(wsb);
  osf_main<<<NWG, NT, 0, stream>>>(A, B, Qm, R, K, phi, sig, phs, M0, Ms, x0, W0,
                                   (float*)d_out, wsb);
}